// Round 17
// baseline (587.251 us; speedup 1.0000x reference)
//
#include <hip/hip_runtime.h>
#include <math.h>

#define NPIX 16384
#define EPSF 1e-8f

typedef float f32x4 __attribute__((ext_vector_type(4)));
typedef short s16x8 __attribute__((ext_vector_type(8)));

__device__ __forceinline__ float wred64(float s){
  s += __shfl_xor(s, 32); s += __shfl_xor(s, 16); s += __shfl_xor(s, 8);
  s += __shfl_xor(s, 4);  s += __shfl_xor(s, 2);  s += __shfl_xor(s, 1);
  return s;
}
__device__ __forceinline__ float rdlane(float v, int l){
  return __int_as_float(__builtin_amdgcn_readlane(__float_as_int(v), l));
}
__device__ __forceinline__ float dot4f(float4 a, float4 b, float acc){
  acc = fmaf(a.x,b.x,acc); acc = fmaf(a.y,b.y,acc);
  acc = fmaf(a.z,b.z,acc); acc = fmaf(a.w,b.w,acc);
  return acc;
}
// split fp32 into bf16 hi + bf16 lo (RNE both), x ~= hi + lo
__device__ __forceinline__ void bf16split(float v, unsigned short &hi, unsigned short &lo){
  unsigned u = __float_as_uint(v);
  unsigned r = u + 0x7FFFu + ((u >> 16) & 1u);
  hi = (unsigned short)(r >> 16);
  float hf = __uint_as_float(((unsigned)hi) << 16);
  float l = v - hf;
  unsigned u2 = __float_as_uint(l);
  unsigned r2 = u2 + 0x7FFFu + ((u2 >> 16) & 1u);
  lo = (unsigned short)(r2 >> 16);
}
// pack normalized component (|v|<=1 pre-scaled by 32767) to int16 with clamp
__device__ __forceinline__ unsigned pk16(float x){
  x = fminf(fmaxf(x, -32767.f), 32767.f);
  return (unsigned)((int)rintf(x)) & 0xffffu;
}

// ---- prep: split conv weights to bf16 hi/lo in MFMA-fragment order; proj weights; zero stats ----
__global__ __launch_bounds__(256) void prep_kernel(const float* __restrict__ w_bb2, const float* __restrict__ w_k1,
                            const float* __restrict__ w_k2, const float* __restrict__ w_q1,
                            const float* __restrict__ w_q2, const float* __restrict__ w_kp,
                            const float* __restrict__ w_qp, unsigned short* __restrict__ wh,
                            unsigned short* __restrict__ wl, float* __restrict__ wtp,
                            float* __restrict__ stats){
  int gid = blockIdx.x*256 + threadIdx.x;
  if (gid < 184320){
    int j = gid & 7;
    int t1 = gid >> 3;
    int lane = t1 & 63;
    int t2 = t1 >> 6;
    int kb = t2 % 18;
    int t3 = t2 / 18;
    int ct = t3 & 3;
    int c  = t3 >> 2;
    const float* src = c==0? w_bb2 : c==1? w_k1 : c==2? w_k2 : c==3? w_q1 : w_q2;
    int cout = ct*16 + (lane & 15);
    int k = kb*32 + (lane>>4)*8 + j;
    float v = src[k*64 + cout];
    unsigned short h,l; bf16split(v,h,l);
    wh[gid] = h; wl[gid] = l;
  } else if (gid < 192512){
    int t = gid - 184320; int which = t >> 12; int d = t & 4095;
    const float* src = which ? w_qp : w_kp;
    int k = d & 3, cout = (d>>2) & 63, cin4 = d >> 8;
    wtp[t] = src[(cin4*4 + k)*64 + cout];
  } else if (gid < 193024){
    stats[gid - 192512] = 0.f;
  }
}

// ---------------- conv1: 3x3, Cin=3 -> 64 (wave = 8 px x 64 cout) ----------------
__global__ __launch_bounds__(256) void conv1_kernel(const float* __restrict__ x, const float* __restrict__ w,
                                                    const float* __restrict__ bias, float* __restrict__ out){
  int wv = blockIdx.x*4 + (threadIdx.x >> 6);
  int c  = threadIdx.x & 63;
  int p0 = wv << 3;
  int ub = __builtin_amdgcn_readfirstlane(p0);
  int b  = ub >> 14; int i0 = ub & (NPIX-1);
  int y  = i0 >> 7, x0 = i0 & 127;
  float wv_[9][3];
  #pragma unroll
  for (int t=0;t<9;++t)
    #pragma unroll
    for (int ci=0;ci<3;++ci) wv_[t][ci] = w[(t*3+ci)*64 + c];
  float bv = bias[c];
  float acc[8];
  #pragma unroll
  for (int p=0;p<8;++p) acc[p] = bv;
  for (int ky=0; ky<3; ++ky){
    int ny = y + ky - 1;
    if ((unsigned)ny >= 128u) continue;
    const float* rowp = x + ((b<<14) + ny*128)*3;
    for (int kx=0; kx<3; ++kx){
      int t = ky*3 + kx;
      #pragma unroll
      for (int p=0;p<8;++p){
        int col = x0 + p + kx - 1;
        if ((unsigned)col < 128u){
          const float* ip = rowp + col*3;
          acc[p] = fmaf(ip[0], wv_[t][0], acc[p]);
          acc[p] = fmaf(ip[1], wv_[t][1], acc[p]);
          acc[p] = fmaf(ip[2], wv_[t][2], acc[p]);
        }
      }
    }
  }
  float* op = out + (p0 << 6) + c;
  #pragma unroll
  for (int p=0;p<8;++p) op[p*64] = fmaxf(acc[p], 0.f);
}

// ---------------- MFMA conv3x3 64->64; 64-px tiles, 512 thr; two-phase staging ----------------
__global__ __launch_bounds__(512) void conv3m_kernel(const float* __restrict__ in,
    const unsigned short* __restrict__ wh, const unsigned short* __restrict__ wl,
    const float* __restrict__ bias, int relu, float* __restrict__ out){
  __shared__ char smem[50688];            // lhi[25344B] + llo[25344B]; lout aliases after MFMA
  float* lout = (float*)smem;
  int blk = blockIdx.x;                   // 512 = b(2) * y(128) * xh(2)
  int xh = blk & 1, y = (blk>>1) & 127, b = blk >> 8;
  int x0 = xh << 6;
  int tid = threadIdx.x;
  float4 tv[7];
  #pragma unroll
  for (int i=0;i<7;++i){
    int s = tid + (i<<9);
    float4 t = {0.f,0.f,0.f,0.f};
    if (s < 3168){
      int pr = s >> 4, cq = s & 15;
      int ky = pr / 66, px = pr - ky*66;
      int ny = y + ky - 1, gx = x0 - 1 + px;
      if ((unsigned)ny < 128u && (unsigned)gx < 128u)
        t = *(const float4*)(in + (((b<<14) + ny*128 + gx)<<6) + (cq<<2));
    }
    tv[i] = t;
  }
  #pragma unroll
  for (int i=0;i<7;++i){
    int s = tid + (i<<9);
    if (s < 3168){
      int pr = s >> 4, cq = s & 15;
      float4 t = tv[i];
      unsigned short h0,l0,h1,l1,h2,l2,h3,l3;
      bf16split(t.x,h0,l0); bf16split(t.y,h1,l1); bf16split(t.z,h2,l2); bf16split(t.w,h3,l3);
      int slot = (cq >> 1) ^ (pr & 7);
      int byte = pr*128 + (slot<<4) + ((cq & 1) << 3);
      *(uint2*)(smem + byte) = make_uint2((unsigned)h0 | ((unsigned)h1<<16),
                                          (unsigned)h2 | ((unsigned)h3<<16));
      *(uint2*)(smem + 25344 + byte) = make_uint2((unsigned)l0 | ((unsigned)l1<<16),
                                                  (unsigned)l2 | ((unsigned)l3<<16));
    }
  }
  __syncthreads();
  int lane = tid & 63, wid = tid >> 6;
  int pxsub = wid & 3, ch = wid >> 2;
  int col16 = lane & 15, kgrp = lane >> 4;
  f32x4 acc0 = {0.f,0.f,0.f,0.f}, acc1 = acc0, acl0 = acc0, acl1 = acc0;
  int abase = (ch*2*18)*512 + lane*8;
  #pragma unroll
  for (int kb=0; kb<18; ++kb){
    int tap = kb >> 1;
    int ky = (tap >= 6) ? 2 : (tap >= 3 ? 1 : 0);
    int kx = tap - ky*3;
    int pr = ky*66 + pxsub*16 + col16 + kx;
    int ci0 = ((kb & 1) << 5) + (kgrp << 3);
    int byte = pr*128 + ((((ci0 >> 3) ^ (pr & 7))) << 4);
    s16x8 Bh = *(const s16x8*)(smem + byte);
    s16x8 Bl = *(const s16x8*)(smem + 25344 + byte);
    int ao = abase + kb*512;
    s16x8 Ah0 = *(const s16x8*)(wh + ao);
    s16x8 Al0 = *(const s16x8*)(wl + ao);
    s16x8 Ah1 = *(const s16x8*)(wh + ao + 9216);
    s16x8 Al1 = *(const s16x8*)(wl + ao + 9216);
    acc0 = __builtin_amdgcn_mfma_f32_16x16x32_bf16(Ah0, Bh, acc0, 0, 0, 0);
    acl0 = __builtin_amdgcn_mfma_f32_16x16x32_bf16(Ah0, Bl, acl0, 0, 0, 0);
    acc1 = __builtin_amdgcn_mfma_f32_16x16x32_bf16(Ah1, Bh, acc1, 0, 0, 0);
    acl1 = __builtin_amdgcn_mfma_f32_16x16x32_bf16(Ah1, Bl, acl1, 0, 0, 0);
    acl0 = __builtin_amdgcn_mfma_f32_16x16x32_bf16(Al0, Bh, acl0, 0, 0, 0);
    acl1 = __builtin_amdgcn_mfma_f32_16x16x32_bf16(Al1, Bh, acl1, 0, 0, 0);
  }
  acc0 = acc0 + acl0;
  acc1 = acc1 + acl1;
  __syncthreads();
  int pxl = pxsub*16 + col16;
  int co0 = ch*32 + kgrp*4;
  *(f32x4*)(lout + pxl*68 + co0)      = acc0;
  *(f32x4*)(lout + pxl*68 + co0 + 16) = acc1;
  __syncthreads();
  {
    int px = tid >> 3, c8 = (tid & 7) << 3;
    const float* lp = lout + px*68 + c8;
    float r0[8];
    #pragma unroll
    for (int j=0;j<8;++j) r0[j] = lp[j];
    if (bias){
      #pragma unroll
      for (int j=0;j<8;++j) r0[j] += bias[c8+j];
    }
    if (relu){
      #pragma unroll
      for (int j=0;j<8;++j) r0[j] = fmaxf(r0[j], 0.f);
    }
    float* op = out + (((b<<14) + y*128 + x0 + px)<<6) + c8;
    #pragma unroll
    for (int j=0;j<8;++j) op[j] = r0[j];
  }
}

// ---------------- DUAL MFMA conv3x3 (k1+q1), 64-px tiles, fused stats, two-phase staging ----------------
__global__ __launch_bounds__(512) void conv3m2_kernel(const float* __restrict__ in,
    const unsigned short* __restrict__ whA, const unsigned short* __restrict__ wlA,
    const unsigned short* __restrict__ whB, const unsigned short* __restrict__ wlB,
    float* __restrict__ outA, float* __restrict__ ostA,
    float* __restrict__ outB, float* __restrict__ ostB){
  __shared__ char smem[50688];
  float* loutA = (float*)smem;
  float* loutB = (float*)smem + 4352;
  __shared__ float ls1A[64], ls2A[64], ls1B[64], ls2B[64];
  int blk = blockIdx.x;                   // 512
  int xh = blk & 1, y = (blk>>1) & 127, b = blk >> 8;
  int x0 = xh << 6;
  int tid = threadIdx.x;
  if (tid < 64){ ls1A[tid]=0.f; ls2A[tid]=0.f; ls1B[tid]=0.f; ls2B[tid]=0.f; }
  float4 tv[7];
  #pragma unroll
  for (int i=0;i<7;++i){
    int s = tid + (i<<9);
    float4 t = {0.f,0.f,0.f,0.f};
    if (s < 3168){
      int pr = s >> 4, cq = s & 15;
      int ky = pr / 66, px = pr - ky*66;
      int ny = y + ky - 1, gx = x0 - 1 + px;
      if ((unsigned)ny < 128u && (unsigned)gx < 128u)
        t = *(const float4*)(in + (((b<<14) + ny*128 + gx)<<6) + (cq<<2));
    }
    tv[i] = t;
  }
  #pragma unroll
  for (int i=0;i<7;++i){
    int s = tid + (i<<9);
    if (s < 3168){
      int pr = s >> 4, cq = s & 15;
      float4 t = tv[i];
      unsigned short h0,l0,h1,l1,h2,l2,h3,l3;
      bf16split(t.x,h0,l0); bf16split(t.y,h1,l1); bf16split(t.z,h2,l2); bf16split(t.w,h3,l3);
      int slot = (cq >> 1) ^ (pr & 7);
      int byte = pr*128 + (slot<<4) + ((cq & 1) << 3);
      *(uint2*)(smem + byte) = make_uint2((unsigned)h0 | ((unsigned)h1<<16),
                                          (unsigned)h2 | ((unsigned)h3<<16));
      *(uint2*)(smem + 25344 + byte) = make_uint2((unsigned)l0 | ((unsigned)l1<<16),
                                                  (unsigned)l2 | ((unsigned)l3<<16));
    }
  }
  __syncthreads();
  int lane = tid & 63, wid = tid >> 6;
  int pxsub = wid & 3, ch = wid >> 2;
  int col16 = lane & 15, kgrp = lane >> 4;
  f32x4 z = {0.f,0.f,0.f,0.f};
  f32x4 aA0=z, aA1=z, lA0=z, lA1=z, aB0=z, aB1=z, lB0=z, lB1=z;
  int abase = (ch*2*18)*512 + lane*8;
  #pragma unroll
  for (int kb=0; kb<18; ++kb){
    int tap = kb >> 1;
    int ky = (tap >= 6) ? 2 : (tap >= 3 ? 1 : 0);
    int kx = tap - ky*3;
    int pr = ky*66 + pxsub*16 + col16 + kx;
    int ci0 = ((kb & 1) << 5) + (kgrp << 3);
    int byte = pr*128 + ((((ci0 >> 3) ^ (pr & 7))) << 4);
    s16x8 Bh = *(const s16x8*)(smem + byte);
    s16x8 Bl = *(const s16x8*)(smem + 25344 + byte);
    int ao = abase + kb*512;
    s16x8 AhA0 = *(const s16x8*)(whA + ao);
    s16x8 AlA0 = *(const s16x8*)(wlA + ao);
    s16x8 AhA1 = *(const s16x8*)(whA + ao + 9216);
    s16x8 AlA1 = *(const s16x8*)(wlA + ao + 9216);
    s16x8 AhB0 = *(const s16x8*)(whB + ao);
    s16x8 AlB0 = *(const s16x8*)(wlB + ao);
    s16x8 AhB1 = *(const s16x8*)(whB + ao + 9216);
    s16x8 AlB1 = *(const s16x8*)(wlB + ao + 9216);
    aA0 = __builtin_amdgcn_mfma_f32_16x16x32_bf16(AhA0, Bh, aA0, 0, 0, 0);
    lA0 = __builtin_amdgcn_mfma_f32_16x16x32_bf16(AhA0, Bl, lA0, 0, 0, 0);
    aA1 = __builtin_amdgcn_mfma_f32_16x16x32_bf16(AhA1, Bh, aA1, 0, 0, 0);
    lA1 = __builtin_amdgcn_mfma_f32_16x16x32_bf16(AhA1, Bl, lA1, 0, 0, 0);
    lA0 = __builtin_amdgcn_mfma_f32_16x16x32_bf16(AlA0, Bh, lA0, 0, 0, 0);
    lA1 = __builtin_amdgcn_mfma_f32_16x16x32_bf16(AlA1, Bh, lA1, 0, 0, 0);
    aB0 = __builtin_amdgcn_mfma_f32_16x16x32_bf16(AhB0, Bh, aB0, 0, 0, 0);
    lB0 = __builtin_amdgcn_mfma_f32_16x16x32_bf16(AhB0, Bl, lB0, 0, 0, 0);
    aB1 = __builtin_amdgcn_mfma_f32_16x16x32_bf16(AhB1, Bh, aB1, 0, 0, 0);
    lB1 = __builtin_amdgcn_mfma_f32_16x16x32_bf16(AhB1, Bl, lB1, 0, 0, 0);
    lB0 = __builtin_amdgcn_mfma_f32_16x16x32_bf16(AlB0, Bh, lB0, 0, 0, 0);
    lB1 = __builtin_amdgcn_mfma_f32_16x16x32_bf16(AlB1, Bh, lB1, 0, 0, 0);
  }
  aA0 = aA0 + lA0; aA1 = aA1 + lA1;
  aB0 = aB0 + lB0; aB1 = aB1 + lB1;
  __syncthreads();
  int pxl = pxsub*16 + col16;
  int co0 = ch*32 + kgrp*4;
  *(f32x4*)(loutA + pxl*68 + co0)      = aA0;
  *(f32x4*)(loutA + pxl*68 + co0 + 16) = aA1;
  *(f32x4*)(loutB + pxl*68 + co0)      = aB0;
  *(f32x4*)(loutB + pxl*68 + co0 + 16) = aB1;
  __syncthreads();
  {
    int px = tid >> 3, c8 = (tid & 7) << 3;
    int lane2 = tid & 63;
    float rA[8], rB[8];
    #pragma unroll
    for (int j=0;j<8;++j){ rA[j] = loutA[px*68 + c8 + j]; rB[j] = loutB[px*68 + c8 + j]; }
    float* opA = outA + (((b<<14) + y*128 + x0 + px)<<6) + c8;
    float* opB = outB + (((b<<14) + y*128 + x0 + px)<<6) + c8;
    #pragma unroll
    for (int j=0;j<8;++j){ opA[j] = rA[j]; opB[j] = rB[j]; }
    float sA1[8], sA2[8], sB1[8], sB2[8];
    #pragma unroll
    for (int j=0;j<8;++j){ sA1[j]=rA[j]; sA2[j]=rA[j]*rA[j]; sB1[j]=rB[j]; sB2[j]=rB[j]*rB[j]; }
    #pragma unroll
    for (int m=8; m<64; m<<=1){
      #pragma unroll
      for (int j=0;j<8;++j){
        sA1[j] += __shfl_xor(sA1[j], m); sA2[j] += __shfl_xor(sA2[j], m);
        sB1[j] += __shfl_xor(sB1[j], m); sB2[j] += __shfl_xor(sB2[j], m);
      }
    }
    if ((lane2 >> 3) == 0){
      int c0 = (lane2 & 7) << 3;
      #pragma unroll
      for (int j=0;j<8;++j){
        atomicAdd(&ls1A[c0+j], sA1[j]); atomicAdd(&ls2A[c0+j], sA2[j]);
        atomicAdd(&ls1B[c0+j], sB1[j]); atomicAdd(&ls2B[c0+j], sB2[j]);
      }
    }
    __syncthreads();
    if (tid < 64){
      atomicAdd(&ostA[tid], ls1A[tid]); atomicAdd(&ostA[64+tid], ls2A[tid]);
      atomicAdd(&ostB[tid], ls1B[tid]); atomicAdd(&ostB[64+tid], ls2B[tid]);
    }
  }
}

// ---------------- MERGED k2+q2 conv3x3 (1024 blocks); BN-in, stats-out, two-phase staging ----------------
__global__ __launch_bounds__(512) void conv3mD_kernel(const float* __restrict__ inK, const float* __restrict__ inQ,
    const unsigned short* __restrict__ whK, const unsigned short* __restrict__ wlK,
    const unsigned short* __restrict__ whQ, const unsigned short* __restrict__ wlQ,
    float* __restrict__ ST, const float* __restrict__ gk, const float* __restrict__ tk,
    const float* __restrict__ gq, const float* __restrict__ tq,
    float* __restrict__ outK, float* __restrict__ outQ){
  __shared__ char smem[50688];
  float* lout = (float*)smem;
  __shared__ float la[64], lb[64];
  __shared__ float ls1[64], ls2[64];
  int blk = blockIdx.x;                   // 1024
  int half = blk >> 9;
  int inner = blk & 511;
  int xh = inner & 1, y = (inner>>1) & 127, b = inner >> 8;
  int x0 = xh << 6;
  const float* in = half ? inQ : inK;
  const unsigned short* wh = half ? whQ : whK;
  const unsigned short* wl = half ? wlQ : wlK;
  const float* bnst = ST + (half ? 256 : 0);
  const float* bng  = half ? gq : gk;
  const float* bnb  = half ? tq : tk;
  float* out = half ? outQ : outK;
  float* ost = ST + (half ? 384 : 128);
  int tid = threadIdx.x;
  if (tid < 64){
    float mu  = bnst[tid] * (1.f/32768.f);
    float var = bnst[64+tid] * (1.f/32768.f) - mu*mu;
    float a = bng[tid] * rsqrtf(var + 1e-5f);
    la[tid] = a; lb[tid] = bnb[tid] - mu*a;
    ls1[tid] = 0.f; ls2[tid] = 0.f;
  }
  __syncthreads();
  float4 tv[7]; int ok[7];
  #pragma unroll
  for (int i=0;i<7;++i){
    int s = tid + (i<<9);
    float4 t = {0.f,0.f,0.f,0.f};
    int o = 0;
    if (s < 3168){
      int pr = s >> 4, cq = s & 15;
      int ky = pr / 66, px = pr - ky*66;
      int ny = y + ky - 1, gx = x0 - 1 + px;
      if ((unsigned)ny < 128u && (unsigned)gx < 128u){
        t = *(const float4*)(in + (((b<<14) + ny*128 + gx)<<6) + (cq<<2));
        o = 1;
      }
    }
    tv[i] = t; ok[i] = o;
  }
  #pragma unroll
  for (int i=0;i<7;++i){
    int s = tid + (i<<9);
    if (s < 3168){
      int pr = s >> 4, cq = s & 15;
      float v0=0.f, v1=0.f, v2=0.f, v3=0.f;
      if (ok[i]){
        float4 t = tv[i];
        int c0 = cq<<2;
        v0 = fmaxf(fmaf(t.x, la[c0],   lb[c0]),   0.f);
        v1 = fmaxf(fmaf(t.y, la[c0+1], lb[c0+1]), 0.f);
        v2 = fmaxf(fmaf(t.z, la[c0+2], lb[c0+2]), 0.f);
        v3 = fmaxf(fmaf(t.w, la[c0+3], lb[c0+3]), 0.f);
      }
      unsigned short h0,l0,h1,l1,h2,l2,h3,l3;
      bf16split(v0,h0,l0); bf16split(v1,h1,l1); bf16split(v2,h2,l2); bf16split(v3,h3,l3);
      int slot = (cq >> 1) ^ (pr & 7);
      int byte = pr*128 + (slot<<4) + ((cq & 1) << 3);
      *(uint2*)(smem + byte) = make_uint2((unsigned)h0 | ((unsigned)h1<<16),
                                          (unsigned)h2 | ((unsigned)h3<<16));
      *(uint2*)(smem + 25344 + byte) = make_uint2((unsigned)l0 | ((unsigned)l1<<16),
                                                  (unsigned)l2 | ((unsigned)l3<<16));
    }
  }
  __syncthreads();
  int lane = tid & 63, wid = tid >> 6;
  int pxsub = wid & 3, ch = wid >> 2;
  int col16 = lane & 15, kgrp = lane >> 4;
  f32x4 acc0 = {0.f,0.f,0.f,0.f}, acc1 = acc0, acl0 = acc0, acl1 = acc0;
  int abase = (ch*2*18)*512 + lane*8;
  #pragma unroll
  for (int kb=0; kb<18; ++kb){
    int tap = kb >> 1;
    int ky = (tap >= 6) ? 2 : (tap >= 3 ? 1 : 0);
    int kx = tap - ky*3;
    int pr = ky*66 + pxsub*16 + col16 + kx;
    int ci0 = ((kb & 1) << 5) + (kgrp << 3);
    int byte = pr*128 + ((((ci0 >> 3) ^ (pr & 7))) << 4);
    s16x8 Bh = *(const s16x8*)(smem + byte);
    s16x8 Bl = *(const s16x8*)(smem + 25344 + byte);
    int ao = abase + kb*512;
    s16x8 Ah0 = *(const s16x8*)(wh + ao);
    s16x8 Al0 = *(const s16x8*)(wl + ao);
    s16x8 Ah1 = *(const s16x8*)(wh + ao + 9216);
    s16x8 Al1 = *(const s16x8*)(wl + ao + 9216);
    acc0 = __builtin_amdgcn_mfma_f32_16x16x32_bf16(Ah0, Bh, acc0, 0, 0, 0);
    acl0 = __builtin_amdgcn_mfma_f32_16x16x32_bf16(Ah0, Bl, acl0, 0, 0, 0);
    acc1 = __builtin_amdgcn_mfma_f32_16x16x32_bf16(Ah1, Bh, acc1, 0, 0, 0);
    acl1 = __builtin_amdgcn_mfma_f32_16x16x32_bf16(Ah1, Bl, acl1, 0, 0, 0);
    acl0 = __builtin_amdgcn_mfma_f32_16x16x32_bf16(Al0, Bh, acl0, 0, 0, 0);
    acl1 = __builtin_amdgcn_mfma_f32_16x16x32_bf16(Al1, Bh, acl1, 0, 0, 0);
  }
  acc0 = acc0 + acl0;
  acc1 = acc1 + acl1;
  __syncthreads();
  int pxl = pxsub*16 + col16;
  int co0 = ch*32 + kgrp*4;
  *(f32x4*)(lout + pxl*68 + co0)      = acc0;
  *(f32x4*)(lout + pxl*68 + co0 + 16) = acc1;
  __syncthreads();
  {
    int px = tid >> 3, c8 = (tid & 7) << 3;
    const float* lp = lout + px*68 + c8;
    float r0[8];
    #pragma unroll
    for (int j=0;j<8;++j) r0[j] = lp[j];
    float* op = out + (((b<<14) + y*128 + x0 + px)<<6) + c8;
    #pragma unroll
    for (int j=0;j<8;++j) op[j] = r0[j];
    float s1v[8], s2v[8];
    #pragma unroll
    for (int j=0;j<8;++j){ s1v[j] = r0[j]; s2v[j] = r0[j]*r0[j]; }
    #pragma unroll
    for (int m=8; m<64; m<<=1){
      #pragma unroll
      for (int j=0;j<8;++j){ s1v[j] += __shfl_xor(s1v[j], m); s2v[j] += __shfl_xor(s2v[j], m); }
    }
    int lane2 = tid & 63;
    if ((lane2 >> 3) == 0){
      int c0 = (lane2 & 7) << 3;
      #pragma unroll
      for (int j=0;j<8;++j){ atomicAdd(&ls1[c0+j], s1v[j]); atomicAdd(&ls2[c0+j], s2v[j]); }
    }
    __syncthreads();
    if (tid < 64){ atomicAdd(&ost[tid], ls1[tid]); atomicAdd(&ost[64+tid], ls2[tid]); }
  }
}

// ---------------- dual resfuse: k and q in one dispatch (parallel elementwise) ----------------
__global__ __launch_bounds__(256) void resfuse2_kernel(float* __restrict__ tk, float* __restrict__ tq,
                                                       const float* __restrict__ f, const float* __restrict__ ST,
                                                       const float* __restrict__ gk, const float* __restrict__ bk,
                                                       const float* __restrict__ gq, const float* __restrict__ bq){
  int gid = blockIdx.x*256 + threadIdx.x;        // 0..1048575
  int isQ = gid >> 19;
  int idx4 = gid & 524287;
  float* t = isQ ? tq : tk;
  const float* stats = ST + (isQ ? 384 : 128);
  const float* g    = isQ ? gq : gk;
  const float* beta = isQ ? bq : bk;
  float4 v = ((float4*)t)[idx4];
  float4 fv = ((const float4*)f)[idx4];
  int c0 = (idx4 & 15) * 4;
  float a[4], bb[4];
  #pragma unroll
  for (int j=0;j<4;++j){
    int c = c0 + j;
    float mu  = stats[c]    * (1.f/32768.f);
    float var = stats[64+c] * (1.f/32768.f) - mu*mu;
    a[j]  = g[c] * rsqrtf(var + 1e-5f);
    bb[j] = beta[c] - mu*a[j];
  }
  v.x = fmaxf(fv.x + fmaf(v.x, a[0], bb[0]), 0.f);
  v.y = fmaxf(fv.y + fmaf(v.y, a[1], bb[1]), 0.f);
  v.z = fmaxf(fv.z + fmaf(v.z, a[2], bb[2]), 0.f);
  v.w = fmaxf(fv.w + fmaf(v.w, a[3], bb[3]), 0.f);
  ((float4*)t)[idx4] = v;
}

// ---------------- dual 1x1 projection (k then q) + per-pixel L2 norm ----------------
__global__ __launch_bounds__(256) void proj2_kernel(const float* __restrict__ rk, const float* __restrict__ rq,
                                                    const float* __restrict__ wtp, const float* __restrict__ bkp,
                                                    float* __restrict__ outk, float* __restrict__ outq,
                                                    float* __restrict__ nk, float* __restrict__ nq){
  int wvg = blockIdx.x*4 + (threadIdx.x >> 6);    // 0..8191
  int isQ = wvg >> 12;
  int wv = wvg & 4095;
  int c  = threadIdx.x & 63;
  const float* r = isQ ? rq : rk;
  const float* wt1 = wtp + (isQ ? 4096 : 0);
  float* out = isQ ? outq : outk;
  float* nrm = isQ ? nq : nk;
  int p0 = wv << 3;
  int ub = __builtin_amdgcn_readfirstlane(p0);
  const float4* wq = (const float4*)wt1 + c;
  float4 w[16];
  #pragma unroll
  for (int q=0;q<16;++q) w[q] = wq[q*64];
  float bv = isQ ? 0.f : bkp[c];
  #pragma unroll
  for (int p=0;p<8;++p){
    const float* ip = r + ((ub + p) << 6);   // uniform address -> s_load
    float a0 = bv, a1 = 0.f;
    #pragma unroll
    for (int q=0;q<16;q+=2){
      float4 i0 = *(const float4*)(ip + (q<<2));
      float4 i1 = *(const float4*)(ip + ((q+1)<<2));
      a0 = dot4f(i0, w[q],   a0);
      a1 = dot4f(i1, w[q+1], a1);
    }
    float acc = a0 + a1;
    out[((p0+p)<<6) + c] = acc;
    float s = wred64(acc*acc);
    if (c == 0) nrm[p0+p] = sqrtf(s);
  }
}

// ---------------- edge weights: W[b,i,o] = cos-sim(q_i, k_j) for 5x5 offsets ----------------
#define EW_PAD 68
__global__ __launch_bounds__(256) void edge_kernel(const float* __restrict__ qs, const float* __restrict__ ks,
                                                   const float* __restrict__ nq, const float* __restrict__ nk,
                                                   float* __restrict__ W){
  __shared__ float klds[100*EW_PAD];
  __shared__ float qlds[16*EW_PAD];
  int blk = blockIdx.x;              // 2048 = 2 batches * 128 rows * 8
  int b = blk >> 10; int rem = blk & 1023;
  int y = rem >> 3; int x0 = (rem & 7) << 4;
  int tid = threadIdx.x;
  for (int s = tid; s < 1600; s += 256){
    int cin4 = s & 15; int col = (s >> 4) % 20; int r = (s >> 4) / 20;
    int ry = y - 2 + r; ry = ry < 0 ? 0 : (ry > 127 ? 127 : ry);
    int cx = x0 - 2 + col; cx = cx < 0 ? 0 : (cx > 127 ? 127 : cx);
    float4 v = *(const float4*)(ks + (((b<<14) + ry*128 + cx)<<6) + cin4*4);
    *(float4*)(klds + (r*20+col)*EW_PAD + cin4*4) = v;
  }
  {
    int cin4 = tid & 15; int px = tid >> 4;
    float4 v = *(const float4*)(qs + (((b<<14) + y*128 + x0 + px)<<6) + cin4*4);
    *(float4*)(qlds + px*EW_PAD + cin4*4) = v;
  }
  __syncthreads();
  #pragma unroll
  for (int pair=0; pair<2; ++pair){
    int t2 = tid + pair*256;
    int px = t2 >> 5; int o = t2 & 31;
    if (o < 25){
      int dy = o/5 - 2, dx = o%5 - 2;
      int yy = y + dy, xx = x0 + px + dx;
      bool valid = ((unsigned)yy < 128u) && ((unsigned)xx < 128u);
      const float* kq = klds + ((dy+2)*20 + (px+dx+2))*EW_PAD;
      const float* qq = qlds + px*EW_PAD;
      float a0 = 0.f, a1 = 0.f;
      #pragma unroll
      for (int q=0; q<16; q+=2){
        a0 = dot4f(*(const float4*)(qq + q*4),     *(const float4*)(kq + q*4),     a0);
        a1 = dot4f(*(const float4*)(qq + (q+1)*4), *(const float4*)(kq + (q+1)*4), a1);
      }
      float acc = a0 + a1;
      int gp = (b<<14) + y*128 + x0 + px;
      float wv_ = 0.f;
      if (valid){
        int gj = (b<<14) + yy*128 + xx;
        float rq = 1.f / fmaxf(nq[gp], EPSF);
        float rk = 1.f / fmaxf(nk[gj], EPSF);
        wv_ = acc * rq * rk;
      }
      W[gp*25 + o] = wv_;
    }
  }
}

// ---------------- MP first iteration: fp32 h0 -> packed int16 (4 px/wave, 2048 blocks) ----------------
__global__ __launch_bounds__(256) void mp_first_kernel(const float* __restrict__ src, unsigned* __restrict__ dst,
                                                       const float* __restrict__ W){
  int lane = threadIdx.x & 63;
  int wid  = threadIdx.x >> 6;
  int blk  = blockIdx.x;               // 2048
  int xcd = blk & 7, s = blk >> 3;
  int row_id = xcd*32 + (s >> 3);
  int q8 = s & 7;
  int b = row_id >> 7, y = row_id & 127;
  int x0 = ((q8 << 2) + wid) << 2;
  int gp0 = (b << 14) + y*128 + x0;
  int lo = lane < 25 ? lane : 24;
  float wv[4];
  #pragma unroll
  for (int p=0;p<4;++p) wv[p] = W[(gp0+p)*25 + lo];
  const float* rp[5];
  #pragma unroll
  for (int r=0;r<5;++r){
    int ry = y - 2 + r; ry = ry < 0 ? 0 : (ry > 127 ? 127 : ry);
    rp[r] = src + (((b<<14) + ry*128) << 7) + lane;
  }
  float wa[5][5], wb[5][5];
  #pragma unroll
  for (int cc=0; cc<4; ++cc){
    int xc = x0 - 2 + cc; if (xc < 0) xc = 0;
    int off = xc << 7;
    #pragma unroll
    for (int r=0;r<5;++r){ wa[r][cc] = rp[r][off]; wb[r][cc] = rp[r][off + 64]; }
  }
  #pragma unroll
  for (int p=0;p<4;++p){
    int xl = x0 + p + 2; if (xl > 127) xl = 127;
    int off = xl << 7;
    #pragma unroll
    for (int r=0;r<5;++r){ wa[r][4] = rp[r][off]; wb[r][4] = rp[r][off + 64]; }
    float a0 = 0.f, a1 = 0.f;
    #pragma unroll
    for (int r=0;r<5;++r){
      #pragma unroll
      for (int cc=0;cc<5;++cc){
        float w = rdlane(wv[p], r*5+cc);
        a0 = fmaf(w, wa[r][cc], a0);
        a1 = fmaf(w, wb[r][cc], a1);
      }
    }
    float ss = wred64(a0*a0 + a1*a1);
    float sc = 32767.f / fmaxf(sqrtf(ss), EPSF);   // int16 fixed-point scale (cancels in next norm)
    dst[((gp0 + p) << 6) + lane] = (pk16(a1*sc) << 16) | pk16(a0*sc);
    #pragma unroll
    for (int r=0;r<5;++r){
      #pragma unroll
      for (int cc=0;cc<4;++cc){ wa[r][cc] = wa[r][cc+1]; wb[r][cc] = wb[r][cc+1]; }
    }
  }
}

// ---------------- MP iteration: packed int16 -> packed int16 (same BW as bf16, 12x less quant noise) ----------------
__global__ __launch_bounds__(256) void mp_iterb_kernel(const unsigned* __restrict__ src, unsigned* __restrict__ dst,
                                                       const float* __restrict__ W){
  int lane = threadIdx.x & 63;
  int wid  = threadIdx.x >> 6;
  int blk  = blockIdx.x;               // 2048
  int xcd = blk & 7, s = blk >> 3;     // XCD-contiguous rows for L2 locality
  int row_id = xcd*32 + (s >> 3);
  int q8 = s & 7;
  int b = row_id >> 7, y = row_id & 127;
  int x0 = ((q8 << 2) + wid) << 2;
  int gp0 = (b << 14) + y*128 + x0;
  int lo = lane < 25 ? lane : 24;
  float wv[4];
  #pragma unroll
  for (int p=0;p<4;++p) wv[p] = W[(gp0+p)*25 + lo];
  const unsigned* rp[5];
  #pragma unroll
  for (int r=0;r<5;++r){
    int ry = y - 2 + r; ry = ry < 0 ? 0 : (ry > 127 ? 127 : ry);
    rp[r] = src + (((b<<14) + ry*128) << 6) + lane;
  }
  float wa[5][5], wb[5][5];
  #pragma unroll
  for (int cc=0; cc<4; ++cc){
    int xc = x0 - 2 + cc; if (xc < 0) xc = 0;
    int off = xc << 6;
    #pragma unroll
    for (int r=0;r<5;++r){
      unsigned v = rp[r][off];
      wa[r][cc] = (float)(((int)(v << 16)) >> 16);   // sign-extended low int16 (scale cancels)
      wb[r][cc] = (float)((int)v >> 16);
    }
  }
  #pragma unroll
  for (int p=0;p<4;++p){
    int xl = x0 + p + 2; if (xl > 127) xl = 127;
    int off = xl << 6;
    #pragma unroll
    for (int r=0;r<5;++r){
      unsigned v = rp[r][off];
      wa[r][4] = (float)(((int)(v << 16)) >> 16);
      wb[r][4] = (float)((int)v >> 16);
    }
    float a0 = 0.f, a1 = 0.f;
    #pragma unroll
    for (int r=0;r<5;++r){
      #pragma unroll
      for (int cc=0;cc<5;++cc){
        float w = rdlane(wv[p], r*5+cc);
        a0 = fmaf(w, wa[r][cc], a0);
        a1 = fmaf(w, wb[r][cc], a1);
      }
    }
    float ss = wred64(a0*a0 + a1*a1);
    float sc = 32767.f / fmaxf(sqrtf(ss), EPSF);
    dst[((gp0 + p) << 6) + lane] = (pk16(a1*sc) << 16) | pk16(a0*sc);
    #pragma unroll
    for (int r=0;r<5;++r){
      #pragma unroll
      for (int cc=0;cc<4;++cc){ wa[r][cc] = wa[r][cc+1]; wb[r][cc] = wb[r][cc+1]; }
    }
  }
}

// ---------------- last iteration fused with final (int16 src; iter-32 inline + sim/softmax/masks) ----------------
__global__ __launch_bounds__(256) void mp_lastb_kernel(const unsigned* __restrict__ src, const float* __restrict__ W,
                                                       const int* __restrict__ agidx, float* __restrict__ out){
  int lane = threadIdx.x & 63;
  int wid  = threadIdx.x >> 6;
  int blk  = blockIdx.x;               // 1024
  int xcd = blk & 7, s = blk >> 3;
  int row_id = xcd*32 + (s >> 2);
  int q4 = s & 3;
  int b = row_id >> 7, y = row_id & 127;
  int x0 = ((q4 << 2) + wid) << 3;
  int gp0 = (b << 14) + y*128 + x0;
  int lo = lane < 25 ? lane : 24;
  float av0[8], av1[8], isc[8];
  #pragma unroll
  for (int m=0;m<8;++m){
    int ai = agidx[m];
    int ay = ai >> 7, ax = ai & 127;
    float wva = W[((b<<14) + ai)*25 + lo];
    float aa0 = 0.f, aa1 = 0.f;
    #pragma unroll
    for (int r=0;r<5;++r){
      int ry = ay - 2 + r; ry = ry < 0 ? 0 : (ry > 127 ? 127 : ry);
      const unsigned* rp = src + (((b<<14) + ry*128) << 6) + lane;
      #pragma unroll
      for (int cc=0;cc<5;++cc){
        int xc = ax - 2 + cc; xc = xc < 0 ? 0 : (xc > 127 ? 127 : xc);
        unsigned v = rp[xc<<6];
        float w = rdlane(wva, r*5+cc);
        aa0 = fmaf(w, (float)(((int)(v << 16)) >> 16), aa0);
        aa1 = fmaf(w, (float)((int)v >> 16), aa1);
      }
    }
    float ssm = wred64(aa0*aa0 + aa1*aa1);
    isc[m] = 1.f / fmaxf(sqrtf(ssm), EPSF);
    av0[m] = aa0; av1[m] = aa1;
  }
  float wv[8];
  #pragma unroll
  for (int p=0;p<8;++p) wv[p] = W[(gp0+p)*25 + lo];
  const unsigned* rp[5];
  #pragma unroll
  for (int r=0;r<5;++r){
    int ry = y - 2 + r; ry = ry < 0 ? 0 : (ry > 127 ? 127 : ry);
    rp[r] = src + (((b<<14) + ry*128) << 6) + lane;
  }
  float wa[5][5], wb[5][5];
  #pragma unroll
  for (int cc=0; cc<4; ++cc){
    int xc = x0 - 2 + cc; if (xc < 0) xc = 0;
    int off = xc << 6;
    #pragma unroll
    for (int r=0;r<5;++r){
      unsigned v = rp[r][off];
      wa[r][cc] = (float)(((int)(v << 16)) >> 16);
      wb[r][cc] = (float)((int)v >> 16);
    }
  }
  #pragma unroll
  for (int p=0;p<8;++p){
    int xl = x0 + p + 2; if (xl > 127) xl = 127;
    int off = xl << 6;
    #pragma unroll
    for (int r=0;r<5;++r){
      unsigned v = rp[r][off];
      wa[r][4] = (float)(((int)(v << 16)) >> 16);
      wb[r][4] = (float)((int)v >> 16);
    }
    float a0 = 0.f, a1 = 0.f;
    #pragma unroll
    for (int r=0;r<5;++r){
      #pragma unroll
      for (int cc=0;cc<5;++cc){
        float w = rdlane(wv[p], r*5+cc);
        a0 = fmaf(w, wa[r][cc], a0);
        a1 = fmaf(w, wb[r][cc], a1);
      }
    }
    float ss = wred64(a0*a0 + a1*a1);
    float sc = 1.f / fmaxf(sqrtf(ss), EPSF);
    float p0 = a0*sc, p1 = a1*sc;
    float sim[8];
    #pragma unroll
    for (int m=0;m<8;++m)
      sim[m] = wred64(p0*av0[m] + p1*av1[m]) * isc[m];
    float mx = sim[0];
    #pragma unroll
    for (int m=1;m<8;++m) mx = fmaxf(mx, sim[m]);
    float e[8]; float sum = 0.f;
    #pragma unroll
    for (int m=0;m<8;++m){ e[m] = __expf((sim[m]-mx)*10.f); sum += e[m]; }
    float rs = 1.f / sum;
    if (lane < 8){
      float val = e[0];
      #pragma unroll
      for (int m=1;m<8;++m) val = (lane==m) ? e[m] : val;
      out[(((b<<3)+lane)<<14) + y*128 + x0 + p] = val * rs;
    }
    #pragma unroll
    for (int r=0;r<5;++r){
      #pragma unroll
      for (int cc=0;cc<4;++cc){ wa[r][cc] = wa[r][cc+1]; wb[r][cc] = wb[r][cc+1]; }
    }
  }
}

extern "C" void kernel_launch(void* const* d_in, const int* in_sizes, int n_in,
                              void* d_out, int out_size, void* d_ws, size_t ws_size,
                              hipStream_t stream) {
  (void)in_sizes; (void)n_in; (void)out_size; (void)ws_size;
  const float* x     = (const float*)d_in[0];
  const float* w_bb1 = (const float*)d_in[1];
  const float* b_bb1 = (const float*)d_in[2];
  const float* w_bb2 = (const float*)d_in[3];
  const float* b_bb2 = (const float*)d_in[4];
  const float* w_k1  = (const float*)d_in[5];
  const float* g_k1  = (const float*)d_in[6];
  const float* t_k1  = (const float*)d_in[7];
  const float* w_k2  = (const float*)d_in[8];
  const float* g_k2  = (const float*)d_in[9];
  const float* t_k2  = (const float*)d_in[10];
  const float* w_kp  = (const float*)d_in[11];
  const float* b_kp  = (const float*)d_in[12];
  const float* w_q1  = (const float*)d_in[13];
  const float* g_q1  = (const float*)d_in[14];
  const float* t_q1  = (const float*)d_in[15];
  const float* w_q2  = (const float*)d_in[16];
  const float* g_q2  = (const float*)d_in[17];
  const float* t_q2  = (const float*)d_in[18];
  const float* w_qp  = (const float*)d_in[19];
  const float* h0    = (const float*)d_in[20];
  const int*   agidx = (const int*)d_in[23];
  float* out = (float*)d_out;
  float* ws  = (float*)d_ws;

  float* S0 = ws + 0;          // F1, then T2k
  float* S1 = ws + 2097152;    // F
  float* S2 = ws + 4194304;    // T1k, then KS
  float* S3 = ws + 6291456;    // T1q, then QS
  float* S4 = ws + 8388608;    // T2q
  float* WW = ws + 12582912;   // 819200
  float* NK = ws + 13402112;   // 32768
  float* NQ = ws + 13434880;   // 32768
  float* ST = ws + 13467648;   // 512  (k1:0, k2:128, q1:256, q2:384)
  float* WTp = ws + 13470208;  // 8192 (proj: kp@0, qp@4096)
  unsigned short* WH = (unsigned short*)(ws + 13478400);
  unsigned short* WL = WH + 184320;
  unsigned* BA = (unsigned*)(ws + 0);        // int16-packed h (aliases S0; dead by MP time)
  unsigned* BB = (unsigned*)(ws + 2097152);  // aliases S1

  prep_kernel<<<754, 256, 0, stream>>>(w_bb2, w_k1, w_k2, w_q1, w_q2, w_kp, w_qp, WH, WL, WTp, ST);
  conv1_kernel<<<1024, 256, 0, stream>>>(x, w_bb1, b_bb1, S0);
  conv3m_kernel<<<512, 512, 0, stream>>>(S0, WH + 0, WL + 0, b_bb2, 1, S1);
  // k1 + q1 fused (shared staged input), both with fused stats
  conv3m2_kernel<<<512, 512, 0, stream>>>(S1, WH + 36864, WL + 36864, WH + 3*36864, WL + 3*36864,
                                          S2, ST + 0, S3, ST + 256);
  // k2 + q2 merged into ONE dispatch (independent branches)
  conv3mD_kernel<<<1024, 512, 0, stream>>>(S2, S3, WH + 2*36864, WL + 2*36864, WH + 4*36864, WL + 4*36864,
                                           ST, g_k1, t_k1, g_q1, t_q1, S0, S4);
  resfuse2_kernel<<<4096, 256, 0, stream>>>(S0, S4, S1, ST, g_k2, t_k2, g_q2, t_q2);
  proj2_kernel<<<2048, 256, 0, stream>>>(S0, S4, WTp, b_kp, S2, S3, NK, NQ);
  edge_kernel<<<2048, 256, 0, stream>>>(S3, S2, NQ, NK, WW);
  // MP chain: int16 fixed-point h state (same BW as bf16, ~12x less quantization noise —
  // restores accuracy margin that bf16 left at 1.95e-2 vs 2e-2 threshold); 32 iterations
  // as separate launches (cooperative grid.sync is a measured 8x regression on gfx950).
  mp_first_kernel<<<2048, 256, 0, stream>>>(h0, BA, WW);
  const unsigned* sb = BA;
  for (int it = 0; it < 30; ++it){
    unsigned* db = (it & 1) ? BA : BB;
    mp_iterb_kernel<<<2048, 256, 0, stream>>>(sb, db, WW);
    sb = db;
  }
  mp_lastb_kernel<<<1024, 256, 0, stream>>>(sb, WW, agidx, out);
}

// Round 19
// 548.165 us; speedup vs baseline: 1.0713x; 1.0713x over previous
//
#include <hip/hip_runtime.h>
#include <math.h>

#define NPIX 16384
#define EPSF 1e-8f

typedef float f32x4 __attribute__((ext_vector_type(4)));
typedef short s16x8 __attribute__((ext_vector_type(8)));
typedef __fp16 h16x2 __attribute__((ext_vector_type(2)));

__device__ __forceinline__ float wred64(float s){
  s += __shfl_xor(s, 32); s += __shfl_xor(s, 16); s += __shfl_xor(s, 8);
  s += __shfl_xor(s, 4);  s += __shfl_xor(s, 2);  s += __shfl_xor(s, 1);
  return s;
}
__device__ __forceinline__ float rdlane(float v, int l){
  return __int_as_float(__builtin_amdgcn_readlane(__float_as_int(v), l));
}
__device__ __forceinline__ float dot4f(float4 a, float4 b, float acc){
  acc = fmaf(a.x,b.x,acc); acc = fmaf(a.y,b.y,acc);
  acc = fmaf(a.z,b.z,acc); acc = fmaf(a.w,b.w,acc);
  return acc;
}
// split fp32 into bf16 hi + bf16 lo (RNE both), x ~= hi + lo
__device__ __forceinline__ void bf16split(float v, unsigned short &hi, unsigned short &lo){
  unsigned u = __float_as_uint(v);
  unsigned r = u + 0x7FFFu + ((u >> 16) & 1u);
  hi = (unsigned short)(r >> 16);
  float hf = __uint_as_float(((unsigned)hi) << 16);
  float l = v - hf;
  unsigned u2 = __float_as_uint(l);
  unsigned r2 = u2 + 0x7FFFu + ((u2 >> 16) & 1u);
  lo = (unsigned short)(r2 >> 16);
}
// pack two fp32 -> packed fp16 pair (single v_cvt_pkrtz_f16_f32)
__device__ __forceinline__ unsigned packh2(float a, float b){
  h16x2 r = __builtin_amdgcn_cvt_pkrtz(a, b);
  union { h16x2 h; unsigned u; } cv; cv.h = r;
  return cv.u;
}
__device__ __forceinline__ float unpl(unsigned v){
  union { unsigned short s; __fp16 h; } cv; cv.s = (unsigned short)(v & 0xffffu);
  return (float)cv.h;
}
__device__ __forceinline__ float unph(unsigned v){
  union { unsigned short s; __fp16 h; } cv; cv.s = (unsigned short)(v >> 16);
  return (float)cv.h;
}

// ---- prep: split conv weights to bf16 hi/lo in MFMA-fragment order; proj weights; zero stats ----
__global__ __launch_bounds__(256) void prep_kernel(const float* __restrict__ w_bb2, const float* __restrict__ w_k1,
                            const float* __restrict__ w_k2, const float* __restrict__ w_q1,
                            const float* __restrict__ w_q2, const float* __restrict__ w_kp,
                            const float* __restrict__ w_qp, unsigned short* __restrict__ wh,
                            unsigned short* __restrict__ wl, float* __restrict__ wtp,
                            float* __restrict__ stats){
  int gid = blockIdx.x*256 + threadIdx.x;
  if (gid < 184320){
    int j = gid & 7;
    int t1 = gid >> 3;
    int lane = t1 & 63;
    int t2 = t1 >> 6;
    int kb = t2 % 18;
    int t3 = t2 / 18;
    int ct = t3 & 3;
    int c  = t3 >> 2;
    const float* src = c==0? w_bb2 : c==1? w_k1 : c==2? w_k2 : c==3? w_q1 : w_q2;
    int cout = ct*16 + (lane & 15);
    int k = kb*32 + (lane>>4)*8 + j;
    float v = src[k*64 + cout];
    unsigned short h,l; bf16split(v,h,l);
    wh[gid] = h; wl[gid] = l;
  } else if (gid < 192512){
    int t = gid - 184320; int which = t >> 12; int d = t & 4095;
    const float* src = which ? w_qp : w_kp;
    int k = d & 3, cout = (d>>2) & 63, cin4 = d >> 8;
    wtp[t] = src[(cin4*4 + k)*64 + cout];
  } else if (gid < 193024){
    stats[gid - 192512] = 0.f;
  }
}

// ---------------- conv1: 3x3, Cin=3 -> 64 (wave = 8 px x 64 cout) ----------------
__global__ __launch_bounds__(256) void conv1_kernel(const float* __restrict__ x, const float* __restrict__ w,
                                                    const float* __restrict__ bias, float* __restrict__ out){
  int wv = blockIdx.x*4 + (threadIdx.x >> 6);
  int c  = threadIdx.x & 63;
  int p0 = wv << 3;
  int ub = __builtin_amdgcn_readfirstlane(p0);
  int b  = ub >> 14; int i0 = ub & (NPIX-1);
  int y  = i0 >> 7, x0 = i0 & 127;
  float wv_[9][3];
  #pragma unroll
  for (int t=0;t<9;++t)
    #pragma unroll
    for (int ci=0;ci<3;++ci) wv_[t][ci] = w[(t*3+ci)*64 + c];
  float bv = bias[c];
  float acc[8];
  #pragma unroll
  for (int p=0;p<8;++p) acc[p] = bv;
  for (int ky=0; ky<3; ++ky){
    int ny = y + ky - 1;
    if ((unsigned)ny >= 128u) continue;
    const float* rowp = x + ((b<<14) + ny*128)*3;
    for (int kx=0; kx<3; ++kx){
      int t = ky*3 + kx;
      #pragma unroll
      for (int p=0;p<8;++p){
        int col = x0 + p + kx - 1;
        if ((unsigned)col < 128u){
          const float* ip = rowp + col*3;
          acc[p] = fmaf(ip[0], wv_[t][0], acc[p]);
          acc[p] = fmaf(ip[1], wv_[t][1], acc[p]);
          acc[p] = fmaf(ip[2], wv_[t][2], acc[p]);
        }
      }
    }
  }
  float* op = out + (p0 << 6) + c;
  #pragma unroll
  for (int p=0;p<8;++p) op[p*64] = fmaxf(acc[p], 0.f);
}

// ---------------- MFMA conv3x3 64->64; 64-px tiles, 512 thr; two-phase staging ----------------
__global__ __launch_bounds__(512) void conv3m_kernel(const float* __restrict__ in,
    const unsigned short* __restrict__ wh, const unsigned short* __restrict__ wl,
    const float* __restrict__ bias, int relu, float* __restrict__ out){
  __shared__ char smem[50688];            // lhi[25344B] + llo[25344B]; lout aliases after MFMA
  float* lout = (float*)smem;
  int blk = blockIdx.x;                   // 512 = b(2) * y(128) * xh(2)
  int xh = blk & 1, y = (blk>>1) & 127, b = blk >> 8;
  int x0 = xh << 6;
  int tid = threadIdx.x;
  float4 tv[7];
  #pragma unroll
  for (int i=0;i<7;++i){
    int s = tid + (i<<9);
    float4 t = {0.f,0.f,0.f,0.f};
    if (s < 3168){
      int pr = s >> 4, cq = s & 15;
      int ky = pr / 66, px = pr - ky*66;
      int ny = y + ky - 1, gx = x0 - 1 + px;
      if ((unsigned)ny < 128u && (unsigned)gx < 128u)
        t = *(const float4*)(in + (((b<<14) + ny*128 + gx)<<6) + (cq<<2));
    }
    tv[i] = t;
  }
  #pragma unroll
  for (int i=0;i<7;++i){
    int s = tid + (i<<9);
    if (s < 3168){
      int pr = s >> 4, cq = s & 15;
      float4 t = tv[i];
      unsigned short h0,l0,h1,l1,h2,l2,h3,l3;
      bf16split(t.x,h0,l0); bf16split(t.y,h1,l1); bf16split(t.z,h2,l2); bf16split(t.w,h3,l3);
      int slot = (cq >> 1) ^ (pr & 7);
      int byte = pr*128 + (slot<<4) + ((cq & 1) << 3);
      *(uint2*)(smem + byte) = make_uint2((unsigned)h0 | ((unsigned)h1<<16),
                                          (unsigned)h2 | ((unsigned)h3<<16));
      *(uint2*)(smem + 25344 + byte) = make_uint2((unsigned)l0 | ((unsigned)l1<<16),
                                                  (unsigned)l2 | ((unsigned)l3<<16));
    }
  }
  __syncthreads();
  int lane = tid & 63, wid = tid >> 6;
  int pxsub = wid & 3, ch = wid >> 2;
  int col16 = lane & 15, kgrp = lane >> 4;
  f32x4 acc0 = {0.f,0.f,0.f,0.f}, acc1 = acc0, acl0 = acc0, acl1 = acc0;
  int abase = (ch*2*18)*512 + lane*8;
  #pragma unroll
  for (int kb=0; kb<18; ++kb){
    int tap = kb >> 1;
    int ky = (tap >= 6) ? 2 : (tap >= 3 ? 1 : 0);
    int kx = tap - ky*3;
    int pr = ky*66 + pxsub*16 + col16 + kx;
    int ci0 = ((kb & 1) << 5) + (kgrp << 3);
    int byte = pr*128 + ((((ci0 >> 3) ^ (pr & 7))) << 4);
    s16x8 Bh = *(const s16x8*)(smem + byte);
    s16x8 Bl = *(const s16x8*)(smem + 25344 + byte);
    int ao = abase + kb*512;
    s16x8 Ah0 = *(const s16x8*)(wh + ao);
    s16x8 Al0 = *(const s16x8*)(wl + ao);
    s16x8 Ah1 = *(const s16x8*)(wh + ao + 9216);
    s16x8 Al1 = *(const s16x8*)(wl + ao + 9216);
    acc0 = __builtin_amdgcn_mfma_f32_16x16x32_bf16(Ah0, Bh, acc0, 0, 0, 0);
    acl0 = __builtin_amdgcn_mfma_f32_16x16x32_bf16(Ah0, Bl, acl0, 0, 0, 0);
    acc1 = __builtin_amdgcn_mfma_f32_16x16x32_bf16(Ah1, Bh, acc1, 0, 0, 0);
    acl1 = __builtin_amdgcn_mfma_f32_16x16x32_bf16(Ah1, Bl, acl1, 0, 0, 0);
    acl0 = __builtin_amdgcn_mfma_f32_16x16x32_bf16(Al0, Bh, acl0, 0, 0, 0);
    acl1 = __builtin_amdgcn_mfma_f32_16x16x32_bf16(Al1, Bh, acl1, 0, 0, 0);
  }
  acc0 = acc0 + acl0;
  acc1 = acc1 + acl1;
  __syncthreads();
  int pxl = pxsub*16 + col16;
  int co0 = ch*32 + kgrp*4;
  *(f32x4*)(lout + pxl*68 + co0)      = acc0;
  *(f32x4*)(lout + pxl*68 + co0 + 16) = acc1;
  __syncthreads();
  {
    int px = tid >> 3, c8 = (tid & 7) << 3;
    const float* lp = lout + px*68 + c8;
    float r0[8];
    #pragma unroll
    for (int j=0;j<8;++j) r0[j] = lp[j];
    if (bias){
      #pragma unroll
      for (int j=0;j<8;++j) r0[j] += bias[c8+j];
    }
    if (relu){
      #pragma unroll
      for (int j=0;j<8;++j) r0[j] = fmaxf(r0[j], 0.f);
    }
    float* op = out + (((b<<14) + y*128 + x0 + px)<<6) + c8;
    #pragma unroll
    for (int j=0;j<8;++j) op[j] = r0[j];
  }
}

// ---------------- DUAL MFMA conv3x3 (k1+q1), 64-px tiles, fused stats, two-phase staging ----------------
__global__ __launch_bounds__(512) void conv3m2_kernel(const float* __restrict__ in,
    const unsigned short* __restrict__ whA, const unsigned short* __restrict__ wlA,
    const unsigned short* __restrict__ whB, const unsigned short* __restrict__ wlB,
    float* __restrict__ outA, float* __restrict__ ostA,
    float* __restrict__ outB, float* __restrict__ ostB){
  __shared__ char smem[50688];
  float* loutA = (float*)smem;
  float* loutB = (float*)smem + 4352;
  __shared__ float ls1A[64], ls2A[64], ls1B[64], ls2B[64];
  int blk = blockIdx.x;                   // 512
  int xh = blk & 1, y = (blk>>1) & 127, b = blk >> 8;
  int x0 = xh << 6;
  int tid = threadIdx.x;
  if (tid < 64){ ls1A[tid]=0.f; ls2A[tid]=0.f; ls1B[tid]=0.f; ls2B[tid]=0.f; }
  float4 tv[7];
  #pragma unroll
  for (int i=0;i<7;++i){
    int s = tid + (i<<9);
    float4 t = {0.f,0.f,0.f,0.f};
    if (s < 3168){
      int pr = s >> 4, cq = s & 15;
      int ky = pr / 66, px = pr - ky*66;
      int ny = y + ky - 1, gx = x0 - 1 + px;
      if ((unsigned)ny < 128u && (unsigned)gx < 128u)
        t = *(const float4*)(in + (((b<<14) + ny*128 + gx)<<6) + (cq<<2));
    }
    tv[i] = t;
  }
  #pragma unroll
  for (int i=0;i<7;++i){
    int s = tid + (i<<9);
    if (s < 3168){
      int pr = s >> 4, cq = s & 15;
      float4 t = tv[i];
      unsigned short h0,l0,h1,l1,h2,l2,h3,l3;
      bf16split(t.x,h0,l0); bf16split(t.y,h1,l1); bf16split(t.z,h2,l2); bf16split(t.w,h3,l3);
      int slot = (cq >> 1) ^ (pr & 7);
      int byte = pr*128 + (slot<<4) + ((cq & 1) << 3);
      *(uint2*)(smem + byte) = make_uint2((unsigned)h0 | ((unsigned)h1<<16),
                                          (unsigned)h2 | ((unsigned)h3<<16));
      *(uint2*)(smem + 25344 + byte) = make_uint2((unsigned)l0 | ((unsigned)l1<<16),
                                                  (unsigned)l2 | ((unsigned)l3<<16));
    }
  }
  __syncthreads();
  int lane = tid & 63, wid = tid >> 6;
  int pxsub = wid & 3, ch = wid >> 2;
  int col16 = lane & 15, kgrp = lane >> 4;
  f32x4 z = {0.f,0.f,0.f,0.f};
  f32x4 aA0=z, aA1=z, lA0=z, lA1=z, aB0=z, aB1=z, lB0=z, lB1=z;
  int abase = (ch*2*18)*512 + lane*8;
  #pragma unroll
  for (int kb=0; kb<18; ++kb){
    int tap = kb >> 1;
    int ky = (tap >= 6) ? 2 : (tap >= 3 ? 1 : 0);
    int kx = tap - ky*3;
    int pr = ky*66 + pxsub*16 + col16 + kx;
    int ci0 = ((kb & 1) << 5) + (kgrp << 3);
    int byte = pr*128 + ((((ci0 >> 3) ^ (pr & 7))) << 4);
    s16x8 Bh = *(const s16x8*)(smem + byte);
    s16x8 Bl = *(const s16x8*)(smem + 25344 + byte);
    int ao = abase + kb*512;
    s16x8 AhA0 = *(const s16x8*)(whA + ao);
    s16x8 AlA0 = *(const s16x8*)(wlA + ao);
    s16x8 AhA1 = *(const s16x8*)(whA + ao + 9216);
    s16x8 AlA1 = *(const s16x8*)(wlA + ao + 9216);
    s16x8 AhB0 = *(const s16x8*)(whB + ao);
    s16x8 AlB0 = *(const s16x8*)(wlB + ao);
    s16x8 AhB1 = *(const s16x8*)(whB + ao + 9216);
    s16x8 AlB1 = *(const s16x8*)(wlB + ao + 9216);
    aA0 = __builtin_amdgcn_mfma_f32_16x16x32_bf16(AhA0, Bh, aA0, 0, 0, 0);
    lA0 = __builtin_amdgcn_mfma_f32_16x16x32_bf16(AhA0, Bl, lA0, 0, 0, 0);
    aA1 = __builtin_amdgcn_mfma_f32_16x16x32_bf16(AhA1, Bh, aA1, 0, 0, 0);
    lA1 = __builtin_amdgcn_mfma_f32_16x16x32_bf16(AhA1, Bl, lA1, 0, 0, 0);
    lA0 = __builtin_amdgcn_mfma_f32_16x16x32_bf16(AlA0, Bh, lA0, 0, 0, 0);
    lA1 = __builtin_amdgcn_mfma_f32_16x16x32_bf16(AlA1, Bh, lA1, 0, 0, 0);
    aB0 = __builtin_amdgcn_mfma_f32_16x16x32_bf16(AhB0, Bh, aB0, 0, 0, 0);
    lB0 = __builtin_amdgcn_mfma_f32_16x16x32_bf16(AhB0, Bl, lB0, 0, 0, 0);
    aB1 = __builtin_amdgcn_mfma_f32_16x16x32_bf16(AhB1, Bh, aB1, 0, 0, 0);
    lB1 = __builtin_amdgcn_mfma_f32_16x16x32_bf16(AhB1, Bl, lB1, 0, 0, 0);
    lB0 = __builtin_amdgcn_mfma_f32_16x16x32_bf16(AlB0, Bh, lB0, 0, 0, 0);
    lB1 = __builtin_amdgcn_mfma_f32_16x16x32_bf16(AlB1, Bh, lB1, 0, 0, 0);
  }
  aA0 = aA0 + lA0; aA1 = aA1 + lA1;
  aB0 = aB0 + lB0; aB1 = aB1 + lB1;
  __syncthreads();
  int pxl = pxsub*16 + col16;
  int co0 = ch*32 + kgrp*4;
  *(f32x4*)(loutA + pxl*68 + co0)      = aA0;
  *(f32x4*)(loutA + pxl*68 + co0 + 16) = aA1;
  *(f32x4*)(loutB + pxl*68 + co0)      = aB0;
  *(f32x4*)(loutB + pxl*68 + co0 + 16) = aB1;
  __syncthreads();
  {
    int px = tid >> 3, c8 = (tid & 7) << 3;
    int lane2 = tid & 63;
    float rA[8], rB[8];
    #pragma unroll
    for (int j=0;j<8;++j){ rA[j] = loutA[px*68 + c8 + j]; rB[j] = loutB[px*68 + c8 + j]; }
    float* opA = outA + (((b<<14) + y*128 + x0 + px)<<6) + c8;
    float* opB = outB + (((b<<14) + y*128 + x0 + px)<<6) + c8;
    #pragma unroll
    for (int j=0;j<8;++j){ opA[j] = rA[j]; opB[j] = rB[j]; }
    float sA1[8], sA2[8], sB1[8], sB2[8];
    #pragma unroll
    for (int j=0;j<8;++j){ sA1[j]=rA[j]; sA2[j]=rA[j]*rA[j]; sB1[j]=rB[j]; sB2[j]=rB[j]*rB[j]; }
    #pragma unroll
    for (int m=8; m<64; m<<=1){
      #pragma unroll
      for (int j=0;j<8;++j){
        sA1[j] += __shfl_xor(sA1[j], m); sA2[j] += __shfl_xor(sA2[j], m);
        sB1[j] += __shfl_xor(sB1[j], m); sB2[j] += __shfl_xor(sB2[j], m);
      }
    }
    if ((lane2 >> 3) == 0){
      int c0 = (lane2 & 7) << 3;
      #pragma unroll
      for (int j=0;j<8;++j){
        atomicAdd(&ls1A[c0+j], sA1[j]); atomicAdd(&ls2A[c0+j], sA2[j]);
        atomicAdd(&ls1B[c0+j], sB1[j]); atomicAdd(&ls2B[c0+j], sB2[j]);
      }
    }
    __syncthreads();
    if (tid < 64){
      atomicAdd(&ostA[tid], ls1A[tid]); atomicAdd(&ostA[64+tid], ls2A[tid]);
      atomicAdd(&ostB[tid], ls1B[tid]); atomicAdd(&ostB[64+tid], ls2B[tid]);
    }
  }
}

// ---------------- MERGED k2+q2 conv3x3 (1024 blocks); BN-in, stats-out, two-phase staging ----------------
__global__ __launch_bounds__(512) void conv3mD_kernel(const float* __restrict__ inK, const float* __restrict__ inQ,
    const unsigned short* __restrict__ whK, const unsigned short* __restrict__ wlK,
    const unsigned short* __restrict__ whQ, const unsigned short* __restrict__ wlQ,
    float* __restrict__ ST, const float* __restrict__ gk, const float* __restrict__ tk,
    const float* __restrict__ gq, const float* __restrict__ tq,
    float* __restrict__ outK, float* __restrict__ outQ){
  __shared__ char smem[50688];
  float* lout = (float*)smem;
  __shared__ float la[64], lb[64];
  __shared__ float ls1[64], ls2[64];
  int blk = blockIdx.x;                   // 1024
  int half = blk >> 9;
  int inner = blk & 511;
  int xh = inner & 1, y = (inner>>1) & 127, b = inner >> 8;
  int x0 = xh << 6;
  const float* in = half ? inQ : inK;
  const unsigned short* wh = half ? whQ : whK;
  const unsigned short* wl = half ? wlQ : wlK;
  const float* bnst = ST + (half ? 256 : 0);
  const float* bng  = half ? gq : gk;
  const float* bnb  = half ? tq : tk;
  float* out = half ? outQ : outK;
  float* ost = ST + (half ? 384 : 128);
  int tid = threadIdx.x;
  if (tid < 64){
    float mu  = bnst[tid] * (1.f/32768.f);
    float var = bnst[64+tid] * (1.f/32768.f) - mu*mu;
    float a = bng[tid] * rsqrtf(var + 1e-5f);
    la[tid] = a; lb[tid] = bnb[tid] - mu*a;
    ls1[tid] = 0.f; ls2[tid] = 0.f;
  }
  __syncthreads();
  float4 tv[7]; int ok[7];
  #pragma unroll
  for (int i=0;i<7;++i){
    int s = tid + (i<<9);
    float4 t = {0.f,0.f,0.f,0.f};
    int o = 0;
    if (s < 3168){
      int pr = s >> 4, cq = s & 15;
      int ky = pr / 66, px = pr - ky*66;
      int ny = y + ky - 1, gx = x0 - 1 + px;
      if ((unsigned)ny < 128u && (unsigned)gx < 128u){
        t = *(const float4*)(in + (((b<<14) + ny*128 + gx)<<6) + (cq<<2));
        o = 1;
      }
    }
    tv[i] = t; ok[i] = o;
  }
  #pragma unroll
  for (int i=0;i<7;++i){
    int s = tid + (i<<9);
    if (s < 3168){
      int pr = s >> 4, cq = s & 15;
      float v0=0.f, v1=0.f, v2=0.f, v3=0.f;
      if (ok[i]){
        float4 t = tv[i];
        int c0 = cq<<2;
        v0 = fmaxf(fmaf(t.x, la[c0],   lb[c0]),   0.f);
        v1 = fmaxf(fmaf(t.y, la[c0+1], lb[c0+1]), 0.f);
        v2 = fmaxf(fmaf(t.z, la[c0+2], lb[c0+2]), 0.f);
        v3 = fmaxf(fmaf(t.w, la[c0+3], lb[c0+3]), 0.f);
      }
      unsigned short h0,l0,h1,l1,h2,l2,h3,l3;
      bf16split(v0,h0,l0); bf16split(v1,h1,l1); bf16split(v2,h2,l2); bf16split(v3,h3,l3);
      int slot = (cq >> 1) ^ (pr & 7);
      int byte = pr*128 + (slot<<4) + ((cq & 1) << 3);
      *(uint2*)(smem + byte) = make_uint2((unsigned)h0 | ((unsigned)h1<<16),
                                          (unsigned)h2 | ((unsigned)h3<<16));
      *(uint2*)(smem + 25344 + byte) = make_uint2((unsigned)l0 | ((unsigned)l1<<16),
                                                  (unsigned)l2 | ((unsigned)l3<<16));
    }
  }
  __syncthreads();
  int lane = tid & 63, wid = tid >> 6;
  int pxsub = wid & 3, ch = wid >> 2;
  int col16 = lane & 15, kgrp = lane >> 4;
  f32x4 acc0 = {0.f,0.f,0.f,0.f}, acc1 = acc0, acl0 = acc0, acl1 = acc0;
  int abase = (ch*2*18)*512 + lane*8;
  #pragma unroll
  for (int kb=0; kb<18; ++kb){
    int tap = kb >> 1;
    int ky = (tap >= 6) ? 2 : (tap >= 3 ? 1 : 0);
    int kx = tap - ky*3;
    int pr = ky*66 + pxsub*16 + col16 + kx;
    int ci0 = ((kb & 1) << 5) + (kgrp << 3);
    int byte = pr*128 + ((((ci0 >> 3) ^ (pr & 7))) << 4);
    s16x8 Bh = *(const s16x8*)(smem + byte);
    s16x8 Bl = *(const s16x8*)(smem + 25344 + byte);
    int ao = abase + kb*512;
    s16x8 Ah0 = *(const s16x8*)(wh + ao);
    s16x8 Al0 = *(const s16x8*)(wl + ao);
    s16x8 Ah1 = *(const s16x8*)(wh + ao + 9216);
    s16x8 Al1 = *(const s16x8*)(wl + ao + 9216);
    acc0 = __builtin_amdgcn_mfma_f32_16x16x32_bf16(Ah0, Bh, acc0, 0, 0, 0);
    acl0 = __builtin_amdgcn_mfma_f32_16x16x32_bf16(Ah0, Bl, acl0, 0, 0, 0);
    acc1 = __builtin_amdgcn_mfma_f32_16x16x32_bf16(Ah1, Bh, acc1, 0, 0, 0);
    acl1 = __builtin_amdgcn_mfma_f32_16x16x32_bf16(Ah1, Bl, acl1, 0, 0, 0);
    acl0 = __builtin_amdgcn_mfma_f32_16x16x32_bf16(Al0, Bh, acl0, 0, 0, 0);
    acl1 = __builtin_amdgcn_mfma_f32_16x16x32_bf16(Al1, Bh, acl1, 0, 0, 0);
  }
  acc0 = acc0 + acl0;
  acc1 = acc1 + acl1;
  __syncthreads();
  int pxl = pxsub*16 + col16;
  int co0 = ch*32 + kgrp*4;
  *(f32x4*)(lout + pxl*68 + co0)      = acc0;
  *(f32x4*)(lout + pxl*68 + co0 + 16) = acc1;
  __syncthreads();
  {
    int px = tid >> 3, c8 = (tid & 7) << 3;
    const float* lp = lout + px*68 + c8;
    float r0[8];
    #pragma unroll
    for (int j=0;j<8;++j) r0[j] = lp[j];
    float* op = out + (((b<<14) + y*128 + x0 + px)<<6) + c8;
    #pragma unroll
    for (int j=0;j<8;++j) op[j] = r0[j];
    float s1v[8], s2v[8];
    #pragma unroll
    for (int j=0;j<8;++j){ s1v[j] = r0[j]; s2v[j] = r0[j]*r0[j]; }
    #pragma unroll
    for (int m=8; m<64; m<<=1){
      #pragma unroll
      for (int j=0;j<8;++j){ s1v[j] += __shfl_xor(s1v[j], m); s2v[j] += __shfl_xor(s2v[j], m); }
    }
    int lane2 = tid & 63;
    if ((lane2 >> 3) == 0){
      int c0 = (lane2 & 7) << 3;
      #pragma unroll
      for (int j=0;j<8;++j){ atomicAdd(&ls1[c0+j], s1v[j]); atomicAdd(&ls2[c0+j], s2v[j]); }
    }
    __syncthreads();
    if (tid < 64){ atomicAdd(&ost[tid], ls1[tid]); atomicAdd(&ost[64+tid], ls2[tid]); }
  }
}

// ---------------- dual resfuse: k and q in one dispatch (parallel elementwise) ----------------
__global__ __launch_bounds__(256) void resfuse2_kernel(float* __restrict__ tk, float* __restrict__ tq,
                                                       const float* __restrict__ f, const float* __restrict__ ST,
                                                       const float* __restrict__ gk, const float* __restrict__ bk,
                                                       const float* __restrict__ gq, const float* __restrict__ bq){
  int gid = blockIdx.x*256 + threadIdx.x;        // 0..1048575
  int isQ = gid >> 19;
  int idx4 = gid & 524287;
  float* t = isQ ? tq : tk;
  const float* stats = ST + (isQ ? 384 : 128);
  const float* g    = isQ ? gq : gk;
  const float* beta = isQ ? bq : bk;
  float4 v = ((float4*)t)[idx4];
  float4 fv = ((const float4*)f)[idx4];
  int c0 = (idx4 & 15) * 4;
  float a[4], bb[4];
  #pragma unroll
  for (int j=0;j<4;++j){
    int c = c0 + j;
    float mu  = stats[c]    * (1.f/32768.f);
    float var = stats[64+c] * (1.f/32768.f) - mu*mu;
    a[j]  = g[c] * rsqrtf(var + 1e-5f);
    bb[j] = beta[c] - mu*a[j];
  }
  v.x = fmaxf(fv.x + fmaf(v.x, a[0], bb[0]), 0.f);
  v.y = fmaxf(fv.y + fmaf(v.y, a[1], bb[1]), 0.f);
  v.z = fmaxf(fv.z + fmaf(v.z, a[2], bb[2]), 0.f);
  v.w = fmaxf(fv.w + fmaf(v.w, a[3], bb[3]), 0.f);
  ((float4*)t)[idx4] = v;
}

// ---------------- dual 1x1 projection (k then q) + per-pixel L2 norm ----------------
__global__ __launch_bounds__(256) void proj2_kernel(const float* __restrict__ rk, const float* __restrict__ rq,
                                                    const float* __restrict__ wtp, const float* __restrict__ bkp,
                                                    float* __restrict__ outk, float* __restrict__ outq,
                                                    float* __restrict__ nk, float* __restrict__ nq){
  int wvg = blockIdx.x*4 + (threadIdx.x >> 6);    // 0..8191
  int isQ = wvg >> 12;
  int wv = wvg & 4095;
  int c  = threadIdx.x & 63;
  const float* r = isQ ? rq : rk;
  const float* wt1 = wtp + (isQ ? 4096 : 0);
  float* out = isQ ? outq : outk;
  float* nrm = isQ ? nq : nk;
  int p0 = wv << 3;
  int ub = __builtin_amdgcn_readfirstlane(p0);
  const float4* wq = (const float4*)wt1 + c;
  float4 w[16];
  #pragma unroll
  for (int q=0;q<16;++q) w[q] = wq[q*64];
  float bv = isQ ? 0.f : bkp[c];
  #pragma unroll
  for (int p=0;p<8;++p){
    const float* ip = r + ((ub + p) << 6);   // uniform address -> s_load
    float a0 = bv, a1 = 0.f;
    #pragma unroll
    for (int q=0;q<16;q+=2){
      float4 i0 = *(const float4*)(ip + (q<<2));
      float4 i1 = *(const float4*)(ip + ((q+1)<<2));
      a0 = dot4f(i0, w[q],   a0);
      a1 = dot4f(i1, w[q+1], a1);
    }
    float acc = a0 + a1;
    out[((p0+p)<<6) + c] = acc;
    float s = wred64(acc*acc);
    if (c == 0) nrm[p0+p] = sqrtf(s);
  }
}

// ---------------- edge weights: W[b,i,o] = cos-sim(q_i, k_j) for 5x5 offsets ----------------
#define EW_PAD 68
__global__ __launch_bounds__(256) void edge_kernel(const float* __restrict__ qs, const float* __restrict__ ks,
                                                   const float* __restrict__ nq, const float* __restrict__ nk,
                                                   float* __restrict__ W){
  __shared__ float klds[100*EW_PAD];
  __shared__ float qlds[16*EW_PAD];
  int blk = blockIdx.x;              // 2048 = 2 batches * 128 rows * 8
  int b = blk >> 10; int rem = blk & 1023;
  int y = rem >> 3; int x0 = (rem & 7) << 4;
  int tid = threadIdx.x;
  for (int s = tid; s < 1600; s += 256){
    int cin4 = s & 15; int col = (s >> 4) % 20; int r = (s >> 4) / 20;
    int ry = y - 2 + r; ry = ry < 0 ? 0 : (ry > 127 ? 127 : ry);
    int cx = x0 - 2 + col; cx = cx < 0 ? 0 : (cx > 127 ? 127 : cx);
    float4 v = *(const float4*)(ks + (((b<<14) + ry*128 + cx)<<6) + cin4*4);
    *(float4*)(klds + (r*20+col)*EW_PAD + cin4*4) = v;
  }
  {
    int cin4 = tid & 15; int px = tid >> 4;
    float4 v = *(const float4*)(qs + (((b<<14) + y*128 + x0 + px)<<6) + cin4*4);
    *(float4*)(qlds + px*EW_PAD + cin4*4) = v;
  }
  __syncthreads();
  #pragma unroll
  for (int pair=0; pair<2; ++pair){
    int t2 = tid + pair*256;
    int px = t2 >> 5; int o = t2 & 31;
    if (o < 25){
      int dy = o/5 - 2, dx = o%5 - 2;
      int yy = y + dy, xx = x0 + px + dx;
      bool valid = ((unsigned)yy < 128u) && ((unsigned)xx < 128u);
      const float* kq = klds + ((dy+2)*20 + (px+dx+2))*EW_PAD;
      const float* qq = qlds + px*EW_PAD;
      float a0 = 0.f, a1 = 0.f;
      #pragma unroll
      for (int q=0; q<16; q+=2){
        a0 = dot4f(*(const float4*)(qq + q*4),     *(const float4*)(kq + q*4),     a0);
        a1 = dot4f(*(const float4*)(qq + (q+1)*4), *(const float4*)(kq + (q+1)*4), a1);
      }
      float acc = a0 + a1;
      int gp = (b<<14) + y*128 + x0 + px;
      float wv_ = 0.f;
      if (valid){
        int gj = (b<<14) + yy*128 + xx;
        float rq = 1.f / fmaxf(nq[gp], EPSF);
        float rk = 1.f / fmaxf(nk[gj], EPSF);
        wv_ = acc * rq * rk;
      }
      W[gp*25 + o] = wv_;
    }
  }
}

// ---------------- MP first iteration: fp32 h0 -> packed fp16 (4 px/wave, 2048 blocks) ----------------
__global__ __launch_bounds__(256) void mp_first_kernel(const float* __restrict__ src, unsigned* __restrict__ dst,
                                                       const float* __restrict__ W){
  int lane = threadIdx.x & 63;
  int wid  = threadIdx.x >> 6;
  int blk  = blockIdx.x;               // 2048
  int xcd = blk & 7, s = blk >> 3;
  int row_id = xcd*32 + (s >> 3);
  int q8 = s & 7;
  int b = row_id >> 7, y = row_id & 127;
  int x0 = ((q8 << 2) + wid) << 2;
  int gp0 = (b << 14) + y*128 + x0;
  int lo = lane < 25 ? lane : 24;
  float wv[4];
  #pragma unroll
  for (int p=0;p<4;++p) wv[p] = W[(gp0+p)*25 + lo];
  const float* rp[5];
  #pragma unroll
  for (int r=0;r<5;++r){
    int ry = y - 2 + r; ry = ry < 0 ? 0 : (ry > 127 ? 127 : ry);
    rp[r] = src + (((b<<14) + ry*128) << 7) + lane;
  }
  float wa[5][5], wb[5][5];
  #pragma unroll
  for (int cc=0; cc<4; ++cc){
    int xc = x0 - 2 + cc; if (xc < 0) xc = 0;
    int off = xc << 7;
    #pragma unroll
    for (int r=0;r<5;++r){ wa[r][cc] = rp[r][off]; wb[r][cc] = rp[r][off + 64]; }
  }
  #pragma unroll
  for (int p=0;p<4;++p){
    int xl = x0 + p + 2; if (xl > 127) xl = 127;
    int off = xl << 7;
    #pragma unroll
    for (int r=0;r<5;++r){ wa[r][4] = rp[r][off]; wb[r][4] = rp[r][off + 64]; }
    float a0 = 0.f, a1 = 0.f;
    #pragma unroll
    for (int r=0;r<5;++r){
      #pragma unroll
      for (int cc=0;cc<5;++cc){
        float w = rdlane(wv[p], r*5+cc);
        a0 = fmaf(w, wa[r][cc], a0);
        a1 = fmaf(w, wb[r][cc], a1);
      }
    }
    float ss = wred64(a0*a0 + a1*a1);
    float sc = 1.f / fmaxf(sqrtf(ss), EPSF);
    dst[((gp0 + p) << 6) + lane] = packh2(a0*sc, a1*sc);
    #pragma unroll
    for (int r=0;r<5;++r){
      #pragma unroll
      for (int cc=0;cc<4;++cc){ wa[r][cc] = wa[r][cc+1]; wb[r][cc] = wb[r][cc+1]; }
    }
  }
}

// ---------------- MP iteration: packed fp16 -> packed fp16 (bf16-cost conversions, 8x less noise) ----------------
__global__ __launch_bounds__(256) void mp_iterb_kernel(const unsigned* __restrict__ src, unsigned* __restrict__ dst,
                                                       const float* __restrict__ W){
  int lane = threadIdx.x & 63;
  int wid  = threadIdx.x >> 6;
  int blk  = blockIdx.x;               // 2048
  int xcd = blk & 7, s = blk >> 3;     // XCD-contiguous rows for L2 locality
  int row_id = xcd*32 + (s >> 3);
  int q8 = s & 7;
  int b = row_id >> 7, y = row_id & 127;
  int x0 = ((q8 << 2) + wid) << 2;
  int gp0 = (b << 14) + y*128 + x0;
  int lo = lane < 25 ? lane : 24;
  float wv[4];
  #pragma unroll
  for (int p=0;p<4;++p) wv[p] = W[(gp0+p)*25 + lo];
  const unsigned* rp[5];
  #pragma unroll
  for (int r=0;r<5;++r){
    int ry = y - 2 + r; ry = ry < 0 ? 0 : (ry > 127 ? 127 : ry);
    rp[r] = src + (((b<<14) + ry*128) << 6) + lane;
  }
  float wa[5][5], wb[5][5];
  #pragma unroll
  for (int cc=0; cc<4; ++cc){
    int xc = x0 - 2 + cc; if (xc < 0) xc = 0;
    int off = xc << 6;
    #pragma unroll
    for (int r=0;r<5;++r){
      unsigned v = rp[r][off];
      wa[r][cc] = unpl(v);
      wb[r][cc] = unph(v);
    }
  }
  #pragma unroll
  for (int p=0;p<4;++p){
    int xl = x0 + p + 2; if (xl > 127) xl = 127;
    int off = xl << 6;
    #pragma unroll
    for (int r=0;r<5;++r){
      unsigned v = rp[r][off];
      wa[r][4] = unpl(v);
      wb[r][4] = unph(v);
    }
    float a0 = 0.f, a1 = 0.f;
    #pragma unroll
    for (int r=0;r<5;++r){
      #pragma unroll
      for (int cc=0;cc<5;++cc){
        float w = rdlane(wv[p], r*5+cc);
        a0 = fmaf(w, wa[r][cc], a0);
        a1 = fmaf(w, wb[r][cc], a1);
      }
    }
    float ss = wred64(a0*a0 + a1*a1);
    float sc = 1.f / fmaxf(sqrtf(ss), EPSF);
    dst[((gp0 + p) << 6) + lane] = packh2(a0*sc, a1*sc);
    #pragma unroll
    for (int r=0;r<5;++r){
      #pragma unroll
      for (int cc=0;cc<4;++cc){ wa[r][cc] = wa[r][cc+1]; wb[r][cc] = wb[r][cc+1]; }
    }
  }
}

// ---------------- last iteration fused with final (fp16 src; iter-32 inline + sim/softmax/masks) ----------------
__global__ __launch_bounds__(256) void mp_lastb_kernel(const unsigned* __restrict__ src, const float* __restrict__ W,
                                                       const int* __restrict__ agidx, float* __restrict__ out){
  int lane = threadIdx.x & 63;
  int wid  = threadIdx.x >> 6;
  int blk  = blockIdx.x;               // 1024
  int xcd = blk & 7, s = blk >> 3;
  int row_id = xcd*32 + (s >> 2);
  int q4 = s & 3;
  int b = row_id >> 7, y = row_id & 127;
  int x0 = ((q4 << 2) + wid) << 3;
  int gp0 = (b << 14) + y*128 + x0;
  int lo = lane < 25 ? lane : 24;
  float av0[8], av1[8], isc[8];
  #pragma unroll
  for (int m=0;m<8;++m){
    int ai = agidx[m];
    int ay = ai >> 7, ax = ai & 127;
    float wva = W[((b<<14) + ai)*25 + lo];
    float aa0 = 0.f, aa1 = 0.f;
    #pragma unroll
    for (int r=0;r<5;++r){
      int ry = ay - 2 + r; ry = ry < 0 ? 0 : (ry > 127 ? 127 : ry);
      const unsigned* rp = src + (((b<<14) + ry*128) << 6) + lane;
      #pragma unroll
      for (int cc=0;cc<5;++cc){
        int xc = ax - 2 + cc; xc = xc < 0 ? 0 : (xc > 127 ? 127 : xc);
        unsigned v = rp[xc<<6];
        float w = rdlane(wva, r*5+cc);
        aa0 = fmaf(w, unpl(v), aa0);
        aa1 = fmaf(w, unph(v), aa1);
      }
    }
    float ssm = wred64(aa0*aa0 + aa1*aa1);
    isc[m] = 1.f / fmaxf(sqrtf(ssm), EPSF);
    av0[m] = aa0; av1[m] = aa1;
  }
  float wv[8];
  #pragma unroll
  for (int p=0;p<8;++p) wv[p] = W[(gp0+p)*25 + lo];
  const unsigned* rp[5];
  #pragma unroll
  for (int r=0;r<5;++r){
    int ry = y - 2 + r; ry = ry < 0 ? 0 : (ry > 127 ? 127 : ry);
    rp[r] = src + (((b<<14) + ry*128) << 6) + lane;
  }
  float wa[5][5], wb[5][5];
  #pragma unroll
  for (int cc=0; cc<4; ++cc){
    int xc = x0 - 2 + cc; if (xc < 0) xc = 0;
    int off = xc << 6;
    #pragma unroll
    for (int r=0;r<5;++r){
      unsigned v = rp[r][off];
      wa[r][cc] = unpl(v);
      wb[r][cc] = unph(v);
    }
  }
  #pragma unroll
  for (int p=0;p<8;++p){
    int xl = x0 + p + 2; if (xl > 127) xl = 127;
    int off = xl << 6;
    #pragma unroll
    for (int r=0;r<5;++r){
      unsigned v = rp[r][off];
      wa[r][4] = unpl(v);
      wb[r][4] = unph(v);
    }
    float a0 = 0.f, a1 = 0.f;
    #pragma unroll
    for (int r=0;r<5;++r){
      #pragma unroll
      for (int cc=0;cc<5;++cc){
        float w = rdlane(wv[p], r*5+cc);
        a0 = fmaf(w, wa[r][cc], a0);
        a1 = fmaf(w, wb[r][cc], a1);
      }
    }
    float ss = wred64(a0*a0 + a1*a1);
    float sc = 1.f / fmaxf(sqrtf(ss), EPSF);
    float p0 = a0*sc, p1 = a1*sc;
    float sim[8];
    #pragma unroll
    for (int m=0;m<8;++m)
      sim[m] = wred64(p0*av0[m] + p1*av1[m]) * isc[m];
    float mx = sim[0];
    #pragma unroll
    for (int m=1;m<8;++m) mx = fmaxf(mx, sim[m]);
    float e[8]; float sum = 0.f;
    #pragma unroll
    for (int m=0;m<8;++m){ e[m] = __expf((sim[m]-mx)*10.f); sum += e[m]; }
    float rs = 1.f / sum;
    if (lane < 8){
      float val = e[0];
      #pragma unroll
      for (int m=1;m<8;++m) val = (lane==m) ? e[m] : val;
      out[(((b<<3)+lane)<<14) + y*128 + x0 + p] = val * rs;
    }
    #pragma unroll
    for (int r=0;r<5;++r){
      #pragma unroll
      for (int cc=0;cc<4;++cc){ wa[r][cc] = wa[r][cc+1]; wb[r][cc] = wb[r][cc+1]; }
    }
  }
}

extern "C" void kernel_launch(void* const* d_in, const int* in_sizes, int n_in,
                              void* d_out, int out_size, void* d_ws, size_t ws_size,
                              hipStream_t stream) {
  (void)in_sizes; (void)n_in; (void)out_size; (void)ws_size;
  const float* x     = (const float*)d_in[0];
  const float* w_bb1 = (const float*)d_in[1];
  const float* b_bb1 = (const float*)d_in[2];
  const float* w_bb2 = (const float*)d_in[3];
  const float* b_bb2 = (const float*)d_in[4];
  const float* w_k1  = (const float*)d_in[5];
  const float* g_k1  = (const float*)d_in[6];
  const float* t_k1  = (const float*)d_in[7];
  const float* w_k2  = (const float*)d_in[8];
  const float* g_k2  = (const float*)d_in[9];
  const float* t_k2  = (const float*)d_in[10];
  const float* w_kp  = (const float*)d_in[11];
  const float* b_kp  = (const float*)d_in[12];
  const float* w_q1  = (const float*)d_in[13];
  const float* g_q1  = (const float*)d_in[14];
  const float* t_q1  = (const float*)d_in[15];
  const float* w_q2  = (const float*)d_in[16];
  const float* g_q2  = (const float*)d_in[17];
  const float* t_q2  = (const float*)d_in[18];
  const float* w_qp  = (const float*)d_in[19];
  const float* h0    = (const float*)d_in[20];
  const int*   agidx = (const int*)d_in[23];
  float* out = (float*)d_out;
  float* ws  = (float*)d_ws;

  float* S0 = ws + 0;          // F1, then T2k
  float* S1 = ws + 2097152;    // F
  float* S2 = ws + 4194304;    // T1k, then KS
  float* S3 = ws + 6291456;    // T1q, then QS
  float* S4 = ws + 8388608;    // T2q
  float* WW = ws + 12582912;   // 819200
  float* NK = ws + 13402112;   // 32768
  float* NQ = ws + 13434880;   // 32768
  float* ST = ws + 13467648;   // 512  (k1:0, k2:128, q1:256, q2:384)
  float* WTp = ws + 13470208;  // 8192 (proj: kp@0, qp@4096)
  unsigned short* WH = (unsigned short*)(ws + 13478400);
  unsigned short* WL = WH + 184320;
  unsigned* BA = (unsigned*)(ws + 0);        // fp16-packed h (aliases S0; dead by MP time)
  unsigned* BB = (unsigned*)(ws + 2097152);  // aliases S1

  prep_kernel<<<754, 256, 0, stream>>>(w_bb2, w_k1, w_k2, w_q1, w_q2, w_kp, w_qp, WH, WL, WTp, ST);
  conv1_kernel<<<1024, 256, 0, stream>>>(x, w_bb1, b_bb1, S0);
  conv3m_kernel<<<512, 512, 0, stream>>>(S0, WH + 0, WL + 0, b_bb2, 1, S1);
  // k1 + q1 fused (shared staged input), both with fused stats
  conv3m2_kernel<<<512, 512, 0, stream>>>(S1, WH + 36864, WL + 36864, WH + 3*36864, WL + 3*36864,
                                          S2, ST + 0, S3, ST + 256);
  // k2 + q2 merged into ONE dispatch (independent branches)
  conv3mD_kernel<<<1024, 512, 0, stream>>>(S2, S3, WH + 2*36864, WL + 2*36864, WH + 4*36864, WL + 4*36864,
                                           ST, g_k1, t_k1, g_q1, t_q1, S0, S4);
  resfuse2_kernel<<<4096, 256, 0, stream>>>(S0, S4, S1, ST, g_k2, t_k2, g_q2, t_q2);
  proj2_kernel<<<2048, 256, 0, stream>>>(S0, S4, WTp, b_kp, S2, S3, NK, NQ);
  edge_kernel<<<2048, 256, 0, stream>>>(S3, S2, NQ, NK, WW);
  // MP chain: packed fp16 h state — single-instruction pack (v_cvt_pkrtz) and unpack
  // (v_cvt_f32_f16) at ~8x less quantization noise than bf16 (unit-vector components are
  // in fp16's precision sweet spot). 32 iterations as separate launches (cooperative
  // grid.sync is a measured 8x regression on gfx950: per-XCD L2 flush at fences).
  mp_first_kernel<<<2048, 256, 0, stream>>>(h0, BA, WW);
  const unsigned* sb = BA;
  for (int it = 0; it < 30; ++it){
    unsigned* db = (it & 1) ? BA : BB;
    mp_iterb_kernel<<<2048, 256, 0, stream>>>(sb, db, WW);
    sb = db;
  }
  mp_lastb_kernel<<<1024, 256, 0, stream>>>(sb, WW, agidx, out);
}